// Round 6
// baseline (356.922 us; speedup 1.0000x reference)
//
#include <hip/hip_runtime.h>
#include <math.h>

// Problem constants
#define NN   4096   // total nodes
#define HH   256    // hidden
#define NEC  119    // element classes
#define NBC  5      // bond classes
#define NMOL 64     // molecules
#define MAT  64     // atoms per molecule

// output layout (float elements)
#define OFF_ATOM   0
#define SZ_ATOM    (4096*119)          // 487424
#define OFF_BOND   487424
#define SZ_BOND    (258048*5)          // 1290240
#define OFF_VALM   (487424+1290240)    // 1777664
#define SZ_VALM    (4096*4096)         // 16777216
#define OFF_ADJ    (1777664+16777216)  // 18554880

typedef short  bf16x8 __attribute__((ext_vector_type(8)));
typedef float  f32x4  __attribute__((ext_vector_type(4)));

// Branchless gelu: 0.5x(1+erf(x/sqrt2)), erf via A&S 7.1.26 (|err|<=1.5e-7).
__device__ __forceinline__ float gelu_f(float x) {
    float z = fabsf(x) * 0.70710678118654752f;
    float t = __builtin_amdgcn_rcpf(fmaf(0.3275911f, z, 1.0f));
    float p = t * fmaf(t, fmaf(t, fmaf(t, fmaf(t, 1.061405429f, -1.453152027f),
                                       1.421413741f), -0.284496736f), 0.254829592f);
    float er = fmaf(-p, __expf(-z * z), 1.0f);   // erf(|x|/sqrt2)
    float s = copysignf(er, x);
    return 0.5f * x * (1.f + s);
}
__device__ __forceinline__ unsigned short f2bf(float x) {
    unsigned int u = __float_as_uint(x);
    unsigned int r = (u + 0x7fffu + ((u >> 16) & 1u)) >> 16;
    return (unsigned short)r;
}

// ---------------------------------------------------------------------------
// K1 (k_front): blocks 0..1023   = fused atom+valency MLP (4 nodes/block)
//               blocks 1024..2047 = P/Q projection (4 nodes/block)
//               (pq sub-blocks 0..127 pack W2f/W3f; sub-block 128 computes
//                u = bg@bW2 and vb = bbn@bW2 + bb2 for k_back's LN-fold)
// Small blocks + launch_bounds(256,8) -> up to 8 blocks/CU for latency hiding.
// ---------------------------------------------------------------------------
__global__ __launch_bounds__(256, 8) void k_front(
    const float* __restrict__ h,
    const float* __restrict__ aW1, const float* __restrict__ ab1,
    const float* __restrict__ ag,  const float* __restrict__ abn,
    const float* __restrict__ aW2, const float* __restrict__ ab2,
    const float* __restrict__ aW3, const float* __restrict__ ab3,
    const float* __restrict__ maxv, const float* __restrict__ covr,
    const float* __restrict__ vW1, const float* __restrict__ vb1,
    const float* __restrict__ vg,  const float* __restrict__ vbn,
    const float* __restrict__ vW2, const float* __restrict__ vb2,
    const float* __restrict__ vW3, const float* __restrict__ vb3,
    const float* __restrict__ bW1, const float* __restrict__ bb1,
    const float* __restrict__ bW2, const float* __restrict__ bW3,
    const float* __restrict__ bg,  const float* __restrict__ bbn,
    const float* __restrict__ bb2,
    float* __restrict__ logits_out,
    float* __restrict__ ma, float* __restrict__ rad, float* __restrict__ val,
    float* __restrict__ P, float* __restrict__ Q,
    short* __restrict__ W2f, short* __restrict__ W3f,
    float* __restrict__ uu, float* __restrict__ vvb)
{
    // union'd LDS: av path uses all; pq path uses first 1024 floats
    __shared__ float smem[3532];
    float (*hs)[376]   = (float(*)[376])smem;            // 1504
    float (*z1)[256]   = (float(*)[256])(smem + 1504);   // 1024
    float (*z2)[128]   = (float(*)[128])(smem + 2528);   //  512
    float (*llog)[120] = (float(*)[120])(smem + 3040);   //  480
    float (*redbuf)[2] = (float(*)[2])  (smem + 3520);   //    8

    const int t  = threadIdx.x;
    const int wv = t >> 6, ln = t & 63;

    if (blockIdx.x >= 1024) {
        // =================== PQ path ===================
        const int pb = blockIdx.x - 1024;
        const int n0 = pb * 4;

        if (pb < 128) {
            const int id = pb * 256 + t;
            {   // W2f: [256,128] -> B-fragments (32768 entries)
                const int e = id & 7, l = (id >> 3) & 63, ks = (id >> 9) & 7, ct = (id >> 12) & 7;
                const int k = ks * 32 + (l >> 4) * 8 + e;
                const int col = ct * 16 + (l & 15);
                W2f[id] = (short)f2bf(bW2[k * 128 + col]);
            }
            if (id < 2048) {
                const int e = id & 7, l = (id >> 3) & 63, ks = id >> 9;
                const int k = ks * 32 + (l >> 4) * 8 + e;
                const int col = l & 15;
                W3f[id] = (col < NBC) ? (short)f2bf(bW3[k * NBC + col]) : (short)0;
            }
        } else if (pb == 128) {
            // u[d] = sum_c bg[c]*bW2[c][d]; vb[d] = sum_c bbn[c]*bW2[c][d] + bb2[d]
            if (t < 128) {
                float ua = 0.f, va = 0.f;
                for (int c = 0; c < 256; ++c) {
                    float w = bW2[c * 128 + t];
                    ua = fmaf(bg[c],  w, ua);
                    va = fmaf(bbn[c], w, va);
                }
                uu[t]  = ua;
                vvb[t] = va + bb2[t];
            }
        }

        float (*hq)[256] = (float(*)[256])smem;
        for (int idx = t; idx < 4 * 256; idx += 256)
            ((float*)hq)[idx] = h[(size_t)n0 * 256 + idx];
        __syncthreads();

        const int c = t;
        float accp[4], accq[4];
        float b1 = bb1[c];
        #pragma unroll
        for (int r = 0; r < 4; ++r) { accp[r] = b1; accq[r] = 0.f; }
        for (int k4 = 0; k4 < 64; ++k4) {
            const int k = k4 * 4;
            float p0 = bW1[(k + 0) * 256 + c];
            float p1 = bW1[(k + 1) * 256 + c];
            float p2 = bW1[(k + 2) * 256 + c];
            float p3 = bW1[(k + 3) * 256 + c];
            float q0 = bW1[(256 + k + 0) * 256 + c];
            float q1 = bW1[(256 + k + 1) * 256 + c];
            float q2 = bW1[(256 + k + 2) * 256 + c];
            float q3 = bW1[(256 + k + 3) * 256 + c];
            #pragma unroll
            for (int r = 0; r < 4; ++r) {
                float4 hv = *(const float4*)&hq[r][k];
                accp[r] = fmaf(hv.x, p0, accp[r]);
                accp[r] = fmaf(hv.y, p1, accp[r]);
                accp[r] = fmaf(hv.z, p2, accp[r]);
                accp[r] = fmaf(hv.w, p3, accp[r]);
                accq[r] = fmaf(hv.x, q0, accq[r]);
                accq[r] = fmaf(hv.y, q1, accq[r]);
                accq[r] = fmaf(hv.z, q2, accq[r]);
                accq[r] = fmaf(hv.w, q3, accq[r]);
            }
        }
        #pragma unroll
        for (int r = 0; r < 4; ++r) {
            P[(size_t)(n0 + r) * 256 + c] = accp[r];
            Q[(size_t)(n0 + r) * 256 + c] = accq[r];
        }
        return;
    }

    // =================== AV path (4 rows) ===================
    const int n0 = blockIdx.x * 4;

    for (int idx = t; idx < 4 * 256; idx += 256) {
        int r = idx >> 8, cc = idx & 255;
        hs[r][cc] = h[(size_t)(n0 + r) * 256 + cc];
    }
    if (t < 4) hs[t][375] = 0.f;
    __syncthreads();

    // ---- atom layer1 (256->256): thread owns col c ----
    {
        const int c = t;
        float b1 = ab1[c];
        float acc[4];
        #pragma unroll
        for (int r = 0; r < 4; ++r) acc[r] = b1;
        for (int k4 = 0; k4 < 64; ++k4) {
            const int k = k4 * 4;
            float w0 = aW1[(k + 0) * 256 + c];
            float w1 = aW1[(k + 1) * 256 + c];
            float w2 = aW1[(k + 2) * 256 + c];
            float w3 = aW1[(k + 3) * 256 + c];
            #pragma unroll
            for (int r = 0; r < 4; ++r) {
                float4 hv = *(const float4*)&hs[r][k];
                acc[r] = fmaf(hv.x, w0, acc[r]);
                acc[r] = fmaf(hv.y, w1, acc[r]);
                acc[r] = fmaf(hv.z, w2, acc[r]);
                acc[r] = fmaf(hv.w, w3, acc[r]);
            }
        }
        #pragma unroll
        for (int r = 0; r < 4; ++r) z1[r][c] = gelu_f(acc[r]);
    }
    __syncthreads();

    // ---- atom LN stats: wave wv owns row wv ----
    {
        const int r = wv;
        float s = 0.f, s2 = 0.f;
        #pragma unroll
        for (int q = 0; q < 4; ++q) {
            float v = z1[r][ln + q * 64];
            s += v; s2 = fmaf(v, v, s2);
        }
        #pragma unroll
        for (int m = 32; m >= 1; m >>= 1) {
            s  += __shfl_xor(s,  m, 64);
            s2 += __shfl_xor(s2, m, 64);
        }
        if (ln == 0) {
            float mu  = s * (1.f / 256.f);
            float var = s2 * (1.f / 256.f) - mu * mu;
            redbuf[r][0] = mu;
            redbuf[r][1] = rsqrtf(var + 1e-5f);
        }
    }
    __syncthreads();
    {
        const int c = t;
        float g = ag[c], b = abn[c];
        #pragma unroll
        for (int r = 0; r < 4; ++r)
            z1[r][c] = (z1[r][c] - redbuf[r][0]) * redbuf[r][1] * g + b;
    }
    __syncthreads();

    // ---- atom layer2 (256->128), k-split halves ----
    {
        const int c2 = t & 127, kh = t >> 7;
        float acc2[4];
        #pragma unroll
        for (int r = 0; r < 4; ++r) acc2[r] = 0.f;
        const int kb = kh * 128;
        for (int k4 = 0; k4 < 32; ++k4) {
            const int k = kb + k4 * 4;
            float w0 = aW2[(k + 0) * 128 + c2];
            float w1 = aW2[(k + 1) * 128 + c2];
            float w2 = aW2[(k + 2) * 128 + c2];
            float w3 = aW2[(k + 3) * 128 + c2];
            #pragma unroll
            for (int r = 0; r < 4; ++r) {
                float4 zv = *(const float4*)&z1[r][k];
                acc2[r] = fmaf(zv.x, w0, acc2[r]);
                acc2[r] = fmaf(zv.y, w1, acc2[r]);
                acc2[r] = fmaf(zv.z, w2, acc2[r]);
                acc2[r] = fmaf(zv.w, w3, acc2[r]);
            }
        }
        if (kh == 1) {
            #pragma unroll
            for (int r = 0; r < 4; ++r) z2[r][c2] = acc2[r];
        }
        __syncthreads();
        if (kh == 0) {
            float b2 = ab2[c2];
            #pragma unroll
            for (int r = 0; r < 4; ++r)
                z2[r][c2] = gelu_f(acc2[r] + z2[r][c2] + b2);
        }
    }
    __syncthreads();

    // ---- atom layer3 (128->119) ----
    if (t < NEC) {
        const int c = t;
        float b3 = ab3[c];
        float acc3[4];
        #pragma unroll
        for (int r = 0; r < 4; ++r) acc3[r] = b3;
        for (int k4 = 0; k4 < 32; ++k4) {
            const int k = k4 * 4;
            float w0 = aW3[(k + 0) * NEC + c];
            float w1 = aW3[(k + 1) * NEC + c];
            float w2 = aW3[(k + 2) * NEC + c];
            float w3 = aW3[(k + 3) * NEC + c];
            #pragma unroll
            for (int r = 0; r < 4; ++r) {
                float4 zv = *(const float4*)&z2[r][k];
                acc3[r] = fmaf(zv.x, w0, acc3[r]);
                acc3[r] = fmaf(zv.y, w1, acc3[r]);
                acc3[r] = fmaf(zv.z, w2, acc3[r]);
                acc3[r] = fmaf(zv.w, w3, acc3[r]);
            }
        }
        #pragma unroll
        for (int r = 0; r < 4; ++r) {
            llog[r][c] = acc3[r];
            logits_out[(size_t)(n0 + r) * NEC + c] = acc3[r];
        }
    }
    __syncthreads();

    // ---- atom softmax + argmax; probs -> hs[r][256+cc]; wave wv owns row wv ----
    {
        const int r = wv;
        float v1 = llog[r][ln];
        float v2 = (ln + 64 < NEC) ? llog[r][ln + 64] : -1e30f;
        float mx; int mi;
        if (v2 > v1) { mx = v2; mi = ln + 64; } else { mx = v1; mi = ln; }
        #pragma unroll
        for (int m = 32; m >= 1; m >>= 1) {
            float ov = __shfl_xor(mx, m, 64);
            int   oi = __shfl_xor(mi, m, 64);
            if (ov > mx || (ov == mx && oi < mi)) { mx = ov; mi = oi; }
        }
        float e1 = __expf(v1 - mx);
        float e2 = (ln + 64 < NEC) ? __expf(v2 - mx) : 0.f;
        float s = e1 + e2;
        #pragma unroll
        for (int m = 32; m >= 1; m >>= 1) s += __shfl_xor(s, m, 64);
        float inv = __builtin_amdgcn_rcpf(s);
        hs[r][256 + ln] = e1 * inv;
        if (ln + 64 < NEC) hs[r][256 + ln + 64] = e2 * inv;
        if (ln == 0) {
            ma[n0 + r]  = maxv[mi];
            rad[n0 + r] = covr[mi];
        }
    }
    __syncthreads();

    // ---- valency layer1 (375->256): 93 full quads + 3-tail ----
    {
        const int c = t;
        float b1 = vb1[c];
        float acc[4];
        #pragma unroll
        for (int r = 0; r < 4; ++r) acc[r] = b1;
        for (int k4 = 0; k4 < 93; ++k4) {
            const int k = k4 * 4;
            float w0 = vW1[(k + 0) * 256 + c];
            float w1 = vW1[(k + 1) * 256 + c];
            float w2 = vW1[(k + 2) * 256 + c];
            float w3 = vW1[(k + 3) * 256 + c];
            #pragma unroll
            for (int r = 0; r < 4; ++r) {
                float4 hv = *(const float4*)&hs[r][k];
                acc[r] = fmaf(hv.x, w0, acc[r]);
                acc[r] = fmaf(hv.y, w1, acc[r]);
                acc[r] = fmaf(hv.z, w2, acc[r]);
                acc[r] = fmaf(hv.w, w3, acc[r]);
            }
        }
        {
            float w0 = vW1[372 * 256 + c];
            float w1 = vW1[373 * 256 + c];
            float w2 = vW1[374 * 256 + c];
            #pragma unroll
            for (int r = 0; r < 4; ++r) {
                acc[r] = fmaf(hs[r][372], w0, acc[r]);
                acc[r] = fmaf(hs[r][373], w1, acc[r]);
                acc[r] = fmaf(hs[r][374], w2, acc[r]);
            }
        }
        #pragma unroll
        for (int r = 0; r < 4; ++r) z1[r][c] = gelu_f(acc[r]);
    }
    __syncthreads();

    // ---- valency LN ----
    {
        const int r = wv;
        float s = 0.f, s2 = 0.f;
        #pragma unroll
        for (int q = 0; q < 4; ++q) {
            float v = z1[r][ln + q * 64];
            s += v; s2 = fmaf(v, v, s2);
        }
        #pragma unroll
        for (int m = 32; m >= 1; m >>= 1) {
            s  += __shfl_xor(s,  m, 64);
            s2 += __shfl_xor(s2, m, 64);
        }
        if (ln == 0) {
            float mu  = s * (1.f / 256.f);
            float var = s2 * (1.f / 256.f) - mu * mu;
            redbuf[r][0] = mu;
            redbuf[r][1] = rsqrtf(var + 1e-5f);
        }
    }
    __syncthreads();
    {
        const int c = t;
        float g = vg[c], b = vbn[c];
        #pragma unroll
        for (int r = 0; r < 4; ++r)
            z1[r][c] = (z1[r][c] - redbuf[r][0]) * redbuf[r][1] * g + b;
    }
    __syncthreads();

    // ---- valency layer2 (256->128) ----
    {
        const int c2 = t & 127, kh = t >> 7;
        float acc2[4];
        #pragma unroll
        for (int r = 0; r < 4; ++r) acc2[r] = 0.f;
        const int kb = kh * 128;
        for (int k4 = 0; k4 < 32; ++k4) {
            const int k = kb + k4 * 4;
            float w0 = vW2[(k + 0) * 128 + c2];
            float w1 = vW2[(k + 1) * 128 + c2];
            float w2 = vW2[(k + 2) * 128 + c2];
            float w3 = vW2[(k + 3) * 128 + c2];
            #pragma unroll
            for (int r = 0; r < 4; ++r) {
                float4 zv = *(const float4*)&z1[r][k];
                acc2[r] = fmaf(zv.x, w0, acc2[r]);
                acc2[r] = fmaf(zv.y, w1, acc2[r]);
                acc2[r] = fmaf(zv.z, w2, acc2[r]);
                acc2[r] = fmaf(zv.w, w3, acc2[r]);
            }
        }
        if (kh == 1) {
            #pragma unroll
            for (int r = 0; r < 4; ++r) z2[r][c2] = acc2[r];
        }
        __syncthreads();
        if (kh == 0) {
            float b2 = vb2[c2];
            #pragma unroll
            for (int r = 0; r < 4; ++r)
                z2[r][c2] = gelu_f(acc2[r] + z2[r][c2] + b2);
        }
    }
    __syncthreads();

    // ---- valency layer3 (128->1) + softplus ----
    {
        const int r = wv;
        float p = fmaf(z2[r][ln], vW3[ln], z2[r][ln + 64] * vW3[ln + 64]);
        #pragma unroll
        for (int m = 32; m >= 1; m >>= 1) p += __shfl_xor(p, m, 64);
        if (ln == 0) {
            float x = p + vb3[0];
            val[n0 + r] = (x > 15.f) ? x : log1pf(expf(x));
        }
    }
}

// ---------------------------------------------------------------------------
// K2 (k_back): blocks 0..4095 = bond MLP per (b,i); blocks 4096..4607 =
//   valency_constrained rows (8 rows/block).
// Bond path: WAVE-INDEPENDENT (1 barrier total). Lane l of wave wv owns
//   row j = wv*16+(l&15), channels (l>>4)*8+e (+32*ks) — the exact MFMA
//   A-fragment layout. Layer1+gelu -> registers (bf16(G*gam), LN folded into
//   the GEMM epilogue via u = gam@W2, vb = bet@W2+bb2). No Xs LDS, no block
//   barriers, 4 shuffles for LN stats (vs 192).
// ---------------------------------------------------------------------------
__global__ __launch_bounds__(256, 4) void k_back(
    const float* __restrict__ pos, const float* __restrict__ rad,
    const float* __restrict__ P, const float* __restrict__ Q,
    const float* __restrict__ bW1, const float* __restrict__ bg,
    const short* __restrict__ W2f, const short* __restrict__ W3f,
    const float* __restrict__ bb3,
    const float* __restrict__ uu, const float* __restrict__ vvb,
    const float* __restrict__ val, const float* __restrict__ ma,
    float* __restrict__ bond_logits, float* __restrict__ adjacency,
    float* __restrict__ valmat)
{
    __shared__ float posr[64][4];
    __shared__ float Pis[256];
    __shared__ float wst0[256], wst1[256], wst2[256], wst3[256];
    __shared__ float gams[256];
    __shared__ float us_[128], vbs[128];
    __shared__ unsigned short Ys[64 * 128];   // bf16, 16B-chunk XOR swizzle by (row&7)
    __shared__ float Ls[64][5];

    const int t  = threadIdx.x;

    if (blockIdx.x >= 4096) {
        // =================== valmat path ===================
        const int i0 = (blockIdx.x - 4096) * 8;
        const float4* v4 = (const float4*)val;
        for (int rr = 0; rr < 8; ++rr) {
            const int i = i0 + rr;
            const float mi = ma[i];
            float4* o4 = (float4*)(valmat + (size_t)i * 4096);
            for (int j = t; j < 1024; j += 256) {
                float4 v = v4[j];
                float4 r;
                r.x = fminf(v.x, mi); r.y = fminf(v.y, mi);
                r.z = fminf(v.z, mi); r.w = fminf(v.w, mi);
                o4[j] = r;
            }
        }
        return;
    }

    // =================== bond path ===================
    const int bi = blockIdx.x;
    const int b  = bi >> 6, i = bi & 63;
    const int wv = t >> 6, ln = t & 63;
    const int lr = ln & 15, kg = ln >> 4;
    const int node0 = b * 64;
    const int j = wv * 16 + lr;               // this lane's pair row

    // ---- stage (the only barrier) ----
    if (t < 64) {
        int n = node0 + t;
        posr[t][0] = pos[n * 3 + 0];
        posr[t][1] = pos[n * 3 + 1];
        posr[t][2] = pos[n * 3 + 2];
        posr[t][3] = rad[n];
    }
    Pis[t]  = P[(size_t)(node0 + i) * 256 + t];
    wst0[t] = bW1[(size_t)512 * 256 + t];
    wst1[t] = bW1[(size_t)513 * 256 + t];
    wst2[t] = bW1[(size_t)514 * 256 + t];
    wst3[t] = bW1[(size_t)515 * 256 + t];
    gams[t] = bg[t];
    if (t < 128) { us_[t] = uu[t]; vbs[t] = vvb[t]; }
    __syncthreads();

    // ---- geometry for this lane's row ----
    float dx = posr[i][0] - posr[j][0];
    float dy = posr[i][1] - posr[j][1];
    float dz = posr[i][2] - posr[j][2];
    float dist  = sqrtf(fmaf(dx, dx, fmaf(dy, dy, dz * dz)));
    float expd  = posr[i][3] + posr[j][3];
    float ratio = dist * __builtin_amdgcn_rcpf(expd);
    float close = (dist < 3.f) ? 1.f : 0.f;

    // ---- Phase A: layer1+gelu straight into A-fragments (LN folded) ----
    float s = 0.f, s2 = 0.f;
    bf16x8 afr[8];
    const float* Qrow = Q + (size_t)(node0 + j) * 256;
    #pragma unroll
    for (int ks = 0; ks < 8; ++ks) {
        const int base = ks * 32 + kg * 8;
        float4 Pa  = *(const float4*)&Pis[base],  Pb  = *(const float4*)&Pis[base + 4];
        float4 Qa  = *(const float4*)(Qrow + base), Qb = *(const float4*)(Qrow + base + 4);
        float4 w0a = *(const float4*)&wst0[base], w0b = *(const float4*)&wst0[base + 4];
        float4 w1a = *(const float4*)&wst1[base], w1b = *(const float4*)&wst1[base + 4];
        float4 w2a = *(const float4*)&wst2[base], w2b = *(const float4*)&wst2[base + 4];
        float4 w3a = *(const float4*)&wst3[base], w3b = *(const float4*)&wst3[base + 4];
        float4 ga  = *(const float4*)&gams[base], gb  = *(const float4*)&gams[base + 4];
        float g, xg;
        #define LANECH(P_, Q_, W0_, W1_, W2_, W3_, G_, EI) \
            g = P_ + Q_; g = fmaf(W0_, dist, g); g = fmaf(W1_, expd, g); \
            g = fmaf(W2_, ratio, g); g = fmaf(W3_, close, g); g = gelu_f(g); \
            s += g; s2 = fmaf(g, g, s2); xg = g * G_; afr[ks][EI] = (short)f2bf(xg);
        LANECH(Pa.x, Qa.x, w0a.x, w1a.x, w2a.x, w3a.x, ga.x, 0)
        LANECH(Pa.y, Qa.y, w0a.y, w1a.y, w2a.y, w3a.y, ga.y, 1)
        LANECH(Pa.z, Qa.z, w0a.z, w1a.z, w2a.z, w3a.z, ga.z, 2)
        LANECH(Pa.w, Qa.w, w0a.w, w1a.w, w2a.w, w3a.w, ga.w, 3)
        LANECH(Pb.x, Qb.x, w0b.x, w1b.x, w2b.x, w3b.x, gb.x, 4)
        LANECH(Pb.y, Qb.y, w0b.y, w1b.y, w2b.y, w3b.y, gb.y, 5)
        LANECH(Pb.z, Qb.z, w0b.z, w1b.z, w2b.z, w3b.z, gb.z, 6)
        LANECH(Pb.w, Qb.w, w0b.w, w1b.w, w2b.w, w3b.w, gb.w, 7)
        #undef LANECH
    }
    // row stats: reduce over the 4 lanes sharing this row (l^16, l^32)
    s  += __shfl_xor(s,  16, 64);  s  += __shfl_xor(s,  32, 64);
    s2 += __shfl_xor(s2, 16, 64);  s2 += __shfl_xor(s2, 32, 64);
    const float mu   = s * (1.f / 256.f);
    const float rstd = rsqrtf(s2 * (1.f / 256.f) - mu * mu + 1e-5f);

    // ---- Phase B: Yg tile (wave's 16 rows x 128 cols) via MFMA ----
    f32x4 acc[8];
    #pragma unroll
    for (int ct = 0; ct < 8; ++ct) acc[ct] = (f32x4){0.f, 0.f, 0.f, 0.f};
    #pragma unroll
    for (int ks = 0; ks < 8; ++ks) {
        #pragma unroll
        for (int ct = 0; ct < 8; ++ct) {
            bf16x8 bfr = *(const bf16x8*)(W2f + (((size_t)(ct * 8 + ks)) * 64 + ln) * 8);
            acc[ct] = __builtin_amdgcn_mfma_f32_16x16x32_bf16(afr[ks], bfr, acc[ct], 0, 0, 0);
        }
    }

    // ---- epilogue: Y = rstd*Yg - rstd*mu*u + vb; gelu; -> Ys (swizzled) ----
    // D-layout: lane holds col = ct*16+lr, rows kg*4+r. Stats for row q live
    // in lanes with (ln&15)==q -> shfl from lane kg*4+r.
    float rst[4], rm[4];
    #pragma unroll
    for (int r = 0; r < 4; ++r) {
        float sr = __shfl(rstd, kg * 4 + r, 64);
        float mr = __shfl(mu,   kg * 4 + r, 64);
        rst[r] = sr; rm[r] = sr * mr;
    }
    #pragma unroll
    for (int ct = 0; ct < 8; ++ct) {
        const int col = ct * 16 + lr;
        const float ucv = us_[col], vcv = vbs[col];
        #pragma unroll
        for (int r = 0; r < 4; ++r) {
            float y = fmaf(rst[r], acc[ct][r], fmaf(-rm[r], ucv, vcv));
            y = gelu_f(y);
            const int row = wv * 16 + kg * 4 + r;
            const int chunk = col >> 3;
            const int off = row * 256 + ((chunk ^ (row & 7)) << 4) + ((col & 7) << 1);
            *(unsigned short*)((char*)Ys + off) = f2bf(y);
        }
    }
    // no barrier: this wave reads only its own 16 Ys rows below

    // ---- Phase B2: L = Ys @ W3f ----
    {
        f32x4 acc3 = (f32x4){0.f, 0.f, 0.f, 0.f};
        #pragma unroll
        for (int ks = 0; ks < 4; ++ks) {
            bf16x8 bfr = *(const bf16x8*)(W3f + ((size_t)(ks * 64 + ln)) * 8);
            const int row   = wv * 16 + lr;
            const int chunk = ks * 4 + kg;
            const int off   = row * 256 + ((chunk ^ (row & 7)) << 4);
            bf16x8 afr2 = *(const bf16x8*)((char*)Ys + off);
            acc3 = __builtin_amdgcn_mfma_f32_16x16x32_bf16(afr2, bfr, acc3, 0, 0, 0);
        }
        if (lr < NBC) {
            #pragma unroll
            for (int r = 0; r < 4; ++r)
                Ls[wv * 16 + kg * 4 + r][lr] = acc3[r];
        }
    }
    // no barrier: wave reads only its own Ls rows

    // ---- writer: wave wv handles rows wv*16 .. wv*16+15 ----
    const size_t adjbase  = (size_t)bi * 64 * 5;
    const size_t bondbase = ((size_t)b * 4032 + (size_t)i * 63) * 5;
    const float b30 = bb3[0], b31 = bb3[1], b32 = bb3[2], b33 = bb3[3], b34 = bb3[4];
    for (int u = ln; u < 80; u += 64) {
        const int jl = u / 5, o = u - jl * 5;
        const int j2 = wv * 16 + jl;
        float l0 = Ls[j2][0] + b30, l1 = Ls[j2][1] + b31, l2 = Ls[j2][2] + b32;
        float l3 = Ls[j2][3] + b33, l4 = Ls[j2][4] + b34;
        float mx = fmaxf(fmaxf(fmaxf(l0, l1), fmaxf(l2, l3)), l4);
        float e0 = __expf(l0 - mx), e1 = __expf(l1 - mx), e2 = __expf(l2 - mx);
        float e3 = __expf(l3 - mx), e4 = __expf(l4 - mx);
        float inv = __builtin_amdgcn_rcpf(e0 + e1 + e2 + e3 + e4);
        float lo = (o == 0) ? l0 : (o == 1) ? l1 : (o == 2) ? l2 : (o == 3) ? l3 : l4;
        float po = ((o == 0) ? e0 : (o == 1) ? e1 : (o == 2) ? e2 : (o == 3) ? e3 : e4) * inv;
        adjacency[adjbase + (size_t)j2 * 5 + o] = (j2 == i) ? ((o == 0) ? 1.f : 0.f) : po;
        if (j2 != i) {
            const int jj = j2 - (j2 > i ? 1 : 0);
            bond_logits[bondbase + (size_t)jj * 5 + o] = lo;
        }
    }
}

// ---------------------------------------------------------------------------
extern "C" void kernel_launch(void* const* d_in, const int* in_sizes, int n_in,
                              void* d_out, int out_size, void* d_ws, size_t ws_size,
                              hipStream_t stream)
{
    (void)in_sizes; (void)n_in; (void)out_size; (void)ws_size;
    const float* h   = (const float*)d_in[0];
    const float* pos = (const float*)d_in[1];
    // d_in[2] edge_index, d_in[3] batch: unused by the reference forward
    const float* aW1 = (const float*)d_in[4];
    const float* ab1 = (const float*)d_in[5];
    const float* ag  = (const float*)d_in[6];
    const float* abn = (const float*)d_in[7];
    const float* aW2 = (const float*)d_in[8];
    const float* ab2 = (const float*)d_in[9];
    const float* aW3 = (const float*)d_in[10];
    const float* ab3 = (const float*)d_in[11];
    const float* vW1 = (const float*)d_in[12];
    const float* vb1 = (const float*)d_in[13];
    const float* vg  = (const float*)d_in[14];
    const float* vbn = (const float*)d_in[15];
    const float* vW2 = (const float*)d_in[16];
    const float* vb2 = (const float*)d_in[17];
    const float* vW3 = (const float*)d_in[18];
    const float* vb3 = (const float*)d_in[19];
    const float* bW1 = (const float*)d_in[20];
    const float* bb1 = (const float*)d_in[21];
    const float* bg  = (const float*)d_in[22];
    const float* bbn = (const float*)d_in[23];
    const float* bW2 = (const float*)d_in[24];
    const float* bb2 = (const float*)d_in[25];
    const float* bW3 = (const float*)d_in[26];
    const float* bb3 = (const float*)d_in[27];
    const float* mv  = (const float*)d_in[28];
    const float* cr  = (const float*)d_in[29];

    float* out = (float*)d_out;
    float* atom_logits = out + OFF_ATOM;
    float* bond_logits = out + OFF_BOND;
    float* valmat      = out + OFF_VALM;
    float* adjacency   = out + OFF_ADJ;

    float* ws    = (float*)d_ws;
    float* ma    = ws;                  // 4096
    float* rad   = ws + 4096;           // 4096
    float* val   = ws + 8192;           // 4096
    float* Pp    = ws + 12288;          // 1048576
    float* Qq    = ws + 1060864;        // 1048576
    short* W2f   = (short*)(ws + 2109440);   // 32768 bf16 (16384 floats)
    short* W3f   = (short*)(ws + 2125824);   // 2048 bf16 (1024 floats)
    float* uu    = ws + 2126848;        // 128
    float* vvb   = ws + 2126976;        // 128

    k_front<<<2048, 256, 0, stream>>>(h,
        aW1, ab1, ag, abn, aW2, ab2, aW3, ab3, mv, cr,
        vW1, vb1, vg, vbn, vW2, vb2, vW3, vb3,
        bW1, bb1, bW2, bW3, bg, bbn, bb2,
        atom_logits, ma, rad, val, Pp, Qq, W2f, W3f, uu, vvb);
    k_back<<<4608, 256, 0, stream>>>(pos, rad, Pp, Qq, bW1, bg,
                                     W2f, W3f, bb3, uu, vvb, val, ma,
                                     bond_logits, adjacency, valmat);
}

// Round 7
// 299.441 us; speedup vs baseline: 1.1920x; 1.1920x over previous
//
#include <hip/hip_runtime.h>
#include <math.h>

// Problem constants
#define NN   4096
#define HH   256
#define NEC  119
#define NBC  5

// output layout (float elements)
#define OFF_ATOM   0
#define OFF_BOND   487424
#define OFF_VALM   (487424+1290240)    // 1777664
#define OFF_ADJ    (1777664+16777216)  // 18554880

typedef short  bf16x8 __attribute__((ext_vector_type(8)));
typedef float  f32x4  __attribute__((ext_vector_type(4)));

// Branchless gelu: 0.5x(1+erf(x/sqrt2)), erf via A&S 7.1.26 (|err|<=1.5e-7).
__device__ __forceinline__ float gelu_f(float x) {
    float z = fabsf(x) * 0.70710678118654752f;
    float t = __builtin_amdgcn_rcpf(fmaf(0.3275911f, z, 1.0f));
    float p = t * fmaf(t, fmaf(t, fmaf(t, fmaf(t, 1.061405429f, -1.453152027f),
                                       1.421413741f), -0.284496736f), 0.254829592f);
    float er = fmaf(-p, __expf(-z * z), 1.0f);
    float s = copysignf(er, x);
    return 0.5f * x * (1.f + s);
}
__device__ __forceinline__ unsigned short f2bf(float x) {
    unsigned int u = __float_as_uint(x);
    unsigned int r = (u + 0x7fffu + ((u >> 16) & 1u)) >> 16;
    return (unsigned short)r;
}

// ---------------------------------------------------------------------------
// K0: pack all MFMA B-fragments (bf16). Fragment rule for 16x16x32:
//   lane l supplies B[k=ks*32+(l>>4)*8+e][col=ct*16+(l&15)], e=0..7.
// id spaces:
//   [0,131072)        PQf : B=[bW1_P | bW1_Q]  k:256, col:512  (ct<32, ks<8)
//   [131072,229376)   V1f : B=vW1 (375-k pad 384), col:256     (ct<16, ks<12)
//   [229376,262144)   V2vf: B=vW2  k:256, col:128              (ct<8,  ks<8)
//   [262144,294912)   W2f : B=bW2  k:256, col:128
//   [294912,296960)   W3f : B=bW3  k:128, col:5 pad 16
//   block 1160        uu = bg@bW2, vvb = bbn@bW2 + bb2 (LN-fold for k_back)
// ---------------------------------------------------------------------------
__global__ __launch_bounds__(256) void k_prep(
    const float* __restrict__ bW1, const float* __restrict__ bW2,
    const float* __restrict__ bW3, const float* __restrict__ vW1,
    const float* __restrict__ vW2,
    const float* __restrict__ bg, const float* __restrict__ bbn,
    const float* __restrict__ bb2,
    short* __restrict__ PQf, short* __restrict__ V1f, short* __restrict__ V2vf,
    short* __restrict__ W2f, short* __restrict__ W3f,
    float* __restrict__ uu, float* __restrict__ vvb)
{
    const int t = threadIdx.x;
    if (blockIdx.x == 1160) {
        if (t < 128) {
            float ua = 0.f, va = 0.f;
            for (int c = 0; c < 256; ++c) {
                float w = bW2[c * 128 + t];
                ua = fmaf(bg[c],  w, ua);
                va = fmaf(bbn[c], w, va);
            }
            uu[t]  = ua;
            vvb[t] = va + bb2[t];
        }
        return;
    }
    const int id = blockIdx.x * 256 + t;
    if (id < 131072) {
        const int e = id & 7, l = (id >> 3) & 63;
        const int rem = id >> 9, ks = rem & 7, ct = rem >> 3;
        const int k = ks * 32 + (l >> 4) * 8 + e;
        const int col = ct * 16 + (l & 15);
        float v = (col < 256) ? bW1[k * 256 + col] : bW1[(256 + k) * 256 + (col - 256)];
        PQf[id] = (short)f2bf(v);
    } else if (id < 229376) {
        const int id2 = id - 131072;
        const int e = id2 & 7, l = (id2 >> 3) & 63;
        const int rem = id2 >> 9, ks = rem % 12, ct = rem / 12;
        const int kk = ks * 32 + (l >> 4) * 8 + e;
        const int col = ct * 16 + (l & 15);
        V1f[id2] = (kk < 375) ? (short)f2bf(vW1[kk * 256 + col]) : (short)0;
    } else if (id < 262144) {
        const int id3 = id - 229376;
        const int e = id3 & 7, l = (id3 >> 3) & 63;
        const int rem = id3 >> 9, ks = rem & 7, ct = rem >> 3;
        const int k = ks * 32 + (l >> 4) * 8 + e;
        const int col = ct * 16 + (l & 15);
        V2vf[id3] = (short)f2bf(vW2[k * 128 + col]);
    } else if (id < 294912) {
        const int id4 = id - 262144;
        const int e = id4 & 7, l = (id4 >> 3) & 63;
        const int ks = (id4 >> 9) & 7, ct = (id4 >> 12) & 7;
        const int k = ks * 32 + (l >> 4) * 8 + e;
        const int col = ct * 16 + (l & 15);
        W2f[id4] = (short)f2bf(bW2[k * 128 + col]);
    } else if (id < 296960) {
        const int id5 = id - 294912;
        const int e = id5 & 7, l = (id5 >> 3) & 63, ks = id5 >> 9;
        const int k = ks * 32 + (l >> 4) * 8 + e;
        const int col = l & 15;
        W3f[id5] = (col < NBC) ? (short)f2bf(bW3[k * NBC + col]) : (short)0;
    }
}

// ---------------------------------------------------------------------------
// K1: blocks 0..511   = atom MLP fp32 (8 rows) + valency MLP via MFMA bf16
//     blocks 512..1023 = PQ GEMM [4096,256]@[256,512] via MFMA bf16
// Atom stays fp32 (argmax->ma/rad needs exact logit order); valency + PQ are
// precision-tolerant (0.02-scale weights attenuate bf16 noise).
// ---------------------------------------------------------------------------
__global__ __launch_bounds__(256, 3) void k_front(
    const float* __restrict__ h,
    const float* __restrict__ aW1, const float* __restrict__ ab1,
    const float* __restrict__ ag,  const float* __restrict__ abn,
    const float* __restrict__ aW2, const float* __restrict__ ab2,
    const float* __restrict__ aW3, const float* __restrict__ ab3,
    const float* __restrict__ maxv, const float* __restrict__ covr,
    const float* __restrict__ vb1, const float* __restrict__ vg,
    const float* __restrict__ vbn, const float* __restrict__ vb2,
    const float* __restrict__ vW3, const float* __restrict__ vb3,
    const float* __restrict__ bb1,
    const short* __restrict__ PQf, const short* __restrict__ V1f,
    const short* __restrict__ V2vf,
    float* __restrict__ logits_out,
    float* __restrict__ ma, float* __restrict__ rad, float* __restrict__ val,
    float* __restrict__ P, float* __restrict__ Q)
{
    __shared__ __align__(16) char smem[44864];
    float (*hs)[256]   = (float(*)[256])(smem);            // [0,8192)
    unsigned short* hb = (unsigned short*)(smem + 8192);   // [8192,20480)  16x384 bf16 swz
    float (*z1)[256]   = (float(*)[256])(smem + 20480);    // [20480,28672)
    float (*z2)[128]   = (float(*)[128])(smem + 28672);    // [28672,32768)
    float (*llog)[120] = (float(*)[120])(smem + 32768);    // [32768,36608)
    unsigned short* zb = (unsigned short*)(smem + 36608);  // [36608,44800) 16x256 bf16 swz
    float (*redbuf)[2] = (float(*)[2])(smem + 44800);

    const int t  = threadIdx.x;
    const int wv = t >> 6, ln = t & 63;
    const int lr = ln & 15, kg = ln >> 4;

    if (blockIdx.x >= 512) {
        // =================== PQ GEMM path ===================
        unsigned short* hbq = (unsigned short*)smem;   // 64x256 bf16 swz (32KB)
        const int gb  = blockIdx.x - 512;
        const int rt  = gb & 63, ct4 = gb >> 6;        // row-tile, col-tile(64)
        const int n0  = rt * 64, c0 = ct4 * 64;

        // stage h[64,256] -> bf16, 16B-chunk XOR swizzle by (row&7)
        for (int i = 0; i < 16; ++i) {
            const int idx4 = t + 256 * i;
            const int r = idx4 >> 6, k4 = (idx4 & 63) * 4;
            float4 hv = *(const float4*)(h + (size_t)(n0 + r) * 256 + k4);
            ushort4 u;
            u.x = f2bf(hv.x); u.y = f2bf(hv.y); u.z = f2bf(hv.z); u.w = f2bf(hv.w);
            const int off = r * 512 + ((((k4 >> 3) ^ (r & 7))) << 4) + ((k4 & 7) << 1);
            *(ushort4*)((char*)hbq + off) = u;
        }
        __syncthreads();

        const int wr0 = wv * 16;
        f32x4 acc[4];
        #pragma unroll
        for (int ctl = 0; ctl < 4; ++ctl) acc[ctl] = (f32x4){0.f, 0.f, 0.f, 0.f};
        #pragma unroll
        for (int ks = 0; ks < 8; ++ks) {
            const int row = wr0 + lr;
            const int chunk = ks * 4 + kg;
            const int aoff = row * 512 + ((chunk ^ (row & 7)) << 4);
            bf16x8 afr = *(const bf16x8*)((char*)hbq + aoff);
            #pragma unroll
            for (int ctl = 0; ctl < 4; ++ctl) {
                const int ct_pq = ct4 * 4 + ctl;
                bf16x8 bfr = *(const bf16x8*)(PQf + (((size_t)(ct_pq * 8 + ks)) * 64 + ln) * 8);
                acc[ctl] = __builtin_amdgcn_mfma_f32_16x16x32_bf16(afr, bfr, acc[ctl], 0, 0, 0);
            }
        }
        #pragma unroll
        for (int ctl = 0; ctl < 4; ++ctl) {
            const int colg = c0 + ctl * 16 + lr;
            const float bias = (colg < 256) ? bb1[colg] : 0.f;
            #pragma unroll
            for (int r = 0; r < 4; ++r) {
                const int n = n0 + wr0 + kg * 4 + r;
                float v = acc[ctl][r] + bias;
                if (colg < 256) P[(size_t)n * 256 + colg] = v;
                else            Q[(size_t)n * 256 + (colg - 256)] = v;
            }
        }
        return;
    }

    // =================== atom(fp32) + valency(MFMA) path, 8 rows ===================
    const int n0 = blockIdx.x * 8;

    // stage: zero hb fully, zero zb rows 8-15, fill hs + hb(h-part)
    #pragma unroll
    for (int i = 0; i < 3; ++i)
        *(int4*)((char*)hb + (t + 256 * i) * 16) = (int4){0, 0, 0, 0};
    *(int4*)((char*)zb + 4096 + t * 16) = (int4){0, 0, 0, 0};
    for (int i = 0; i < 2; ++i) {
        const int idx4 = t + 256 * i;
        const int r = idx4 >> 6, k4 = (idx4 & 63) * 4;
        float4 hv = *(const float4*)(h + (size_t)(n0 + r) * 256 + k4);
        *(float4*)&hs[r][k4] = hv;
        ushort4 u;
        u.x = f2bf(hv.x); u.y = f2bf(hv.y); u.z = f2bf(hv.z); u.w = f2bf(hv.w);
        const int off = r * 768 + ((((k4 >> 3) ^ (r & 7))) << 4) + ((k4 & 7) << 1);
        *(ushort4*)((char*)hb + off) = u;
    }
    __syncthreads();

    // ---- atom layer1 (256->256) fp32: thread owns col c ----
    {
        const int c = t;
        float b1 = ab1[c];
        float acc[8];
        #pragma unroll
        for (int r = 0; r < 8; ++r) acc[r] = b1;
        for (int k4 = 0; k4 < 64; ++k4) {
            const int k = k4 * 4;
            float w0 = aW1[(k + 0) * 256 + c];
            float w1 = aW1[(k + 1) * 256 + c];
            float w2 = aW1[(k + 2) * 256 + c];
            float w3 = aW1[(k + 3) * 256 + c];
            #pragma unroll
            for (int r = 0; r < 8; ++r) {
                float4 hv = *(const float4*)&hs[r][k];
                acc[r] = fmaf(hv.x, w0, acc[r]);
                acc[r] = fmaf(hv.y, w1, acc[r]);
                acc[r] = fmaf(hv.z, w2, acc[r]);
                acc[r] = fmaf(hv.w, w3, acc[r]);
            }
        }
        #pragma unroll
        for (int r = 0; r < 8; ++r) z1[r][c] = gelu_f(acc[r]);
    }
    __syncthreads();

    // ---- atom LN stats (wave wv owns rows wv*2, wv*2+1) ----
    for (int rr = 0; rr < 2; ++rr) {
        const int r = wv * 2 + rr;
        float s = 0.f, s2 = 0.f;
        #pragma unroll
        for (int q = 0; q < 4; ++q) {
            float v = z1[r][ln + q * 64];
            s += v; s2 = fmaf(v, v, s2);
        }
        #pragma unroll
        for (int m = 32; m >= 1; m >>= 1) {
            s  += __shfl_xor(s,  m, 64);
            s2 += __shfl_xor(s2, m, 64);
        }
        if (ln == 0) {
            float mu  = s * (1.f / 256.f);
            float var = s2 * (1.f / 256.f) - mu * mu;
            redbuf[r][0] = mu;
            redbuf[r][1] = rsqrtf(var + 1e-5f);
        }
    }
    __syncthreads();
    {
        const int c = t;
        float g = ag[c], b = abn[c];
        #pragma unroll
        for (int r = 0; r < 8; ++r)
            z1[r][c] = (z1[r][c] - redbuf[r][0]) * redbuf[r][1] * g + b;
    }
    __syncthreads();

    // ---- atom layer2 (256->128) fp32, k-split halves ----
    {
        const int c2 = t & 127, kh = t >> 7;
        float acc2[8];
        #pragma unroll
        for (int r = 0; r < 8; ++r) acc2[r] = 0.f;
        const int kb = kh * 128;
        for (int k4 = 0; k4 < 32; ++k4) {
            const int k = kb + k4 * 4;
            float w0 = aW2[(k + 0) * 128 + c2];
            float w1 = aW2[(k + 1) * 128 + c2];
            float w2 = aW2[(k + 2) * 128 + c2];
            float w3 = aW2[(k + 3) * 128 + c2];
            #pragma unroll
            for (int r = 0; r < 8; ++r) {
                float4 zv = *(const float4*)&z1[r][k];
                acc2[r] = fmaf(zv.x, w0, acc2[r]);
                acc2[r] = fmaf(zv.y, w1, acc2[r]);
                acc2[r] = fmaf(zv.z, w2, acc2[r]);
                acc2[r] = fmaf(zv.w, w3, acc2[r]);
            }
        }
        if (kh == 1) {
            #pragma unroll
            for (int r = 0; r < 8; ++r) z2[r][c2] = acc2[r];
        }
        __syncthreads();
        if (kh == 0) {
            float b2 = ab2[c2];
            #pragma unroll
            for (int r = 0; r < 8; ++r)
                z2[r][c2] = gelu_f(acc2[r] + z2[r][c2] + b2);
        }
    }
    __syncthreads();

    // ---- atom layer3 (128->119) fp32 ----
    if (t < NEC) {
        const int c = t;
        float b3 = ab3[c];
        float acc3[8];
        #pragma unroll
        for (int r = 0; r < 8; ++r) acc3[r] = b3;
        for (int k4 = 0; k4 < 32; ++k4) {
            const int k = k4 * 4;
            float w0 = aW3[(k + 0) * NEC + c];
            float w1 = aW3[(k + 1) * NEC + c];
            float w2 = aW3[(k + 2) * NEC + c];
            float w3 = aW3[(k + 3) * NEC + c];
            #pragma unroll
            for (int r = 0; r < 8; ++r) {
                float4 zv = *(const float4*)&z2[r][k];
                acc3[r] = fmaf(zv.x, w0, acc3[r]);
                acc3[r] = fmaf(zv.y, w1, acc3[r]);
                acc3[r] = fmaf(zv.z, w2, acc3[r]);
                acc3[r] = fmaf(zv.w, w3, acc3[r]);
            }
        }
        #pragma unroll
        for (int r = 0; r < 8; ++r) {
            llog[r][c] = acc3[r];
            logits_out[(size_t)(n0 + r) * NEC + c] = acc3[r];
        }
    }
    __syncthreads();

    // ---- atom softmax + argmax; probs -> hb[row][256+c] (bf16 swz) ----
    for (int rr = 0; rr < 2; ++rr) {
        const int r = wv * 2 + rr;
        float v1 = llog[r][ln];
        float v2 = (ln + 64 < NEC) ? llog[r][ln + 64] : -1e30f;
        float mx; int mi;
        if (v2 > v1) { mx = v2; mi = ln + 64; } else { mx = v1; mi = ln; }
        #pragma unroll
        for (int m = 32; m >= 1; m >>= 1) {
            float ov = __shfl_xor(mx, m, 64);
            int   oi = __shfl_xor(mi, m, 64);
            if (ov > mx || (ov == mx && oi < mi)) { mx = ov; mi = oi; }
        }
        float e1 = __expf(v1 - mx);
        float e2 = (ln + 64 < NEC) ? __expf(v2 - mx) : 0.f;
        float s = e1 + e2;
        #pragma unroll
        for (int m = 32; m >= 1; m >>= 1) s += __shfl_xor(s, m, 64);
        float inv = __builtin_amdgcn_rcpf(s);
        {
            const int cf = 256 + ln;
            const int off = r * 768 + ((((cf >> 3) ^ (r & 7))) << 4) + ((cf & 7) << 1);
            *(unsigned short*)((char*)hb + off) = f2bf(e1 * inv);
        }
        if (ln + 64 < NEC) {
            const int cf = 256 + ln + 64;
            const int off = r * 768 + ((((cf >> 3) ^ (r & 7))) << 4) + ((cf & 7) << 1);
            *(unsigned short*)((char*)hb + off) = f2bf(e2 * inv);
        }
        if (ln == 0) {
            ma[n0 + r]  = maxv[mi];
            rad[n0 + r] = covr[mi];
        }
    }
    __syncthreads();

    // ---- valency L1 via MFMA: [16(8),384] @ V1f[384,256]; wave wv: 64 cols ----
    {
        f32x4 acc[4];
        #pragma unroll
        for (int ctl = 0; ctl < 4; ++ctl) acc[ctl] = (f32x4){0.f, 0.f, 0.f, 0.f};
        #pragma unroll
        for (int ks = 0; ks < 12; ++ks) {
            const int row = lr;
            const int chunk = ks * 4 + kg;
            const int aoff = row * 768 + ((chunk ^ (row & 7)) << 4);
            bf16x8 afr = *(const bf16x8*)((char*)hb + aoff);
            #pragma unroll
            for (int ctl = 0; ctl < 4; ++ctl) {
                const int ctg = wv * 4 + ctl;
                bf16x8 bfr = *(const bf16x8*)(V1f + (((size_t)(ctg * 12 + ks)) * 64 + ln) * 8);
                acc[ctl] = __builtin_amdgcn_mfma_f32_16x16x32_bf16(afr, bfr, acc[ctl], 0, 0, 0);
            }
        }
        if (kg < 2) {
            #pragma unroll
            for (int ctl = 0; ctl < 4; ++ctl) {
                const int col = (wv * 4 + ctl) * 16 + lr;
                const float b1 = vb1[col];
                #pragma unroll
                for (int r = 0; r < 4; ++r)
                    z1[kg * 4 + r][col] = gelu_f(acc[ctl][r] + b1);
            }
        }
    }
    __syncthreads();

    // ---- valency LN; apply -> zb (bf16 swz) ----
    for (int rr = 0; rr < 2; ++rr) {
        const int r = wv * 2 + rr;
        float s = 0.f, s2 = 0.f;
        #pragma unroll
        for (int q = 0; q < 4; ++q) {
            float v = z1[r][ln + q * 64];
            s += v; s2 = fmaf(v, v, s2);
        }
        #pragma unroll
        for (int m = 32; m >= 1; m >>= 1) {
            s  += __shfl_xor(s,  m, 64);
            s2 += __shfl_xor(s2, m, 64);
        }
        if (ln == 0) {
            float mu  = s * (1.f / 256.f);
            float var = s2 * (1.f / 256.f) - mu * mu;
            redbuf[r][0] = mu;
            redbuf[r][1] = rsqrtf(var + 1e-5f);
        }
    }
    __syncthreads();
    {
        const int c = t;
        float g = vg[c], b = vbn[c];
        #pragma unroll
        for (int r = 0; r < 8; ++r) {
            float v = (z1[r][c] - redbuf[r][0]) * redbuf[r][1] * g + b;
            const int off = r * 512 + ((((c >> 3) ^ (r & 7))) << 4) + ((c & 7) << 1);
            *(unsigned short*)((char*)zb + off) = f2bf(v);
        }
    }
    __syncthreads();

    // ---- valency L2 via MFMA: [16(8),256] @ V2vf[256,128]; wave wv: 32 cols ----
    {
        f32x4 acc2[2];
        #pragma unroll
        for (int c2 = 0; c2 < 2; ++c2) acc2[c2] = (f32x4){0.f, 0.f, 0.f, 0.f};
        #pragma unroll
        for (int ks = 0; ks < 8; ++ks) {
            const int row = lr;
            const int chunk = ks * 4 + kg;
            const int aoff = row * 512 + ((chunk ^ (row & 7)) << 4);
            bf16x8 afr = *(const bf16x8*)((char*)zb + aoff);
            #pragma unroll
            for (int c2 = 0; c2 < 2; ++c2) {
                const int ctg = wv * 2 + c2;
                bf16x8 bfr = *(const bf16x8*)(V2vf + (((size_t)(ctg * 8 + ks)) * 64 + ln) * 8);
                acc2[c2] = __builtin_amdgcn_mfma_f32_16x16x32_bf16(afr, bfr, acc2[c2], 0, 0, 0);
            }
        }
        if (kg < 2) {
            #pragma unroll
            for (int c2 = 0; c2 < 2; ++c2) {
                const int col = (wv * 2 + c2) * 16 + lr;
                const float b2 = vb2[col];
                #pragma unroll
                for (int r = 0; r < 4; ++r)
                    z2[kg * 4 + r][col] = gelu_f(acc2[c2][r] + b2);
            }
        }
    }
    __syncthreads();

    // ---- valency L3 (128->1) + softplus ----
    for (int rr = 0; rr < 2; ++rr) {
        const int r = wv * 2 + rr;
        float p = fmaf(z2[r][ln], vW3[ln], z2[r][ln + 64] * vW3[ln + 64]);
        #pragma unroll
        for (int m = 32; m >= 1; m >>= 1) p += __shfl_xor(p, m, 64);
        if (ln == 0) {
            float x = p + vb3[0];
            val[n0 + r] = (x > 15.f) ? x : log1pf(expf(x));
        }
    }
}

// ---------------------------------------------------------------------------
// K2 (k_back): blocks 0..4095 = bond MLP per (b,i); blocks 4096..4607 =
//   valency_constrained rows (8 rows/block). Wave-independent bond path.
// ---------------------------------------------------------------------------
__global__ __launch_bounds__(256, 4) void k_back(
    const float* __restrict__ pos, const float* __restrict__ rad,
    const float* __restrict__ P, const float* __restrict__ Q,
    const float* __restrict__ bW1, const float* __restrict__ bg,
    const short* __restrict__ W2f, const short* __restrict__ W3f,
    const float* __restrict__ bb3,
    const float* __restrict__ uu, const float* __restrict__ vvb,
    const float* __restrict__ val, const float* __restrict__ ma,
    float* __restrict__ bond_logits, float* __restrict__ adjacency,
    float* __restrict__ valmat)
{
    __shared__ float posr[64][4];
    __shared__ float Pis[256];
    __shared__ float wst0[256], wst1[256], wst2[256], wst3[256];
    __shared__ float gams[256];
    __shared__ float us_[128], vbs[128];
    __shared__ unsigned short Ys[64 * 128];
    __shared__ float Ls[64][5];

    const int t  = threadIdx.x;

    if (blockIdx.x >= 4096) {
        const int i0 = (blockIdx.x - 4096) * 8;
        const float4* v4 = (const float4*)val;
        for (int rr = 0; rr < 8; ++rr) {
            const int i = i0 + rr;
            const float mi = ma[i];
            float4* o4 = (float4*)(valmat + (size_t)i * 4096);
            for (int j = t; j < 1024; j += 256) {
                float4 v = v4[j];
                float4 r;
                r.x = fminf(v.x, mi); r.y = fminf(v.y, mi);
                r.z = fminf(v.z, mi); r.w = fminf(v.w, mi);
                o4[j] = r;
            }
        }
        return;
    }

    const int bi = blockIdx.x;
    const int b  = bi >> 6, i = bi & 63;
    const int wv = t >> 6, ln = t & 63;
    const int lr = ln & 15, kg = ln >> 4;
    const int node0 = b * 64;
    const int j = wv * 16 + lr;

    if (t < 64) {
        int n = node0 + t;
        posr[t][0] = pos[n * 3 + 0];
        posr[t][1] = pos[n * 3 + 1];
        posr[t][2] = pos[n * 3 + 2];
        posr[t][3] = rad[n];
    }
    Pis[t]  = P[(size_t)(node0 + i) * 256 + t];
    wst0[t] = bW1[(size_t)512 * 256 + t];
    wst1[t] = bW1[(size_t)513 * 256 + t];
    wst2[t] = bW1[(size_t)514 * 256 + t];
    wst3[t] = bW1[(size_t)515 * 256 + t];
    gams[t] = bg[t];
    if (t < 128) { us_[t] = uu[t]; vbs[t] = vvb[t]; }
    __syncthreads();

    float dx = posr[i][0] - posr[j][0];
    float dy = posr[i][1] - posr[j][1];
    float dz = posr[i][2] - posr[j][2];
    float dist  = sqrtf(fmaf(dx, dx, fmaf(dy, dy, dz * dz)));
    float expd  = posr[i][3] + posr[j][3];
    float ratio = dist * __builtin_amdgcn_rcpf(expd);
    float close = (dist < 3.f) ? 1.f : 0.f;

    float s = 0.f, s2 = 0.f;
    bf16x8 afr[8];
    const float* Qrow = Q + (size_t)(node0 + j) * 256;
    #pragma unroll
    for (int ks = 0; ks < 8; ++ks) {
        const int base = ks * 32 + kg * 8;
        float4 Pa  = *(const float4*)&Pis[base],  Pb  = *(const float4*)&Pis[base + 4];
        float4 Qa  = *(const float4*)(Qrow + base), Qb = *(const float4*)(Qrow + base + 4);
        float4 w0a = *(const float4*)&wst0[base], w0b = *(const float4*)&wst0[base + 4];
        float4 w1a = *(const float4*)&wst1[base], w1b = *(const float4*)&wst1[base + 4];
        float4 w2a = *(const float4*)&wst2[base], w2b = *(const float4*)&wst2[base + 4];
        float4 w3a = *(const float4*)&wst3[base], w3b = *(const float4*)&wst3[base + 4];
        float4 ga  = *(const float4*)&gams[base], gb  = *(const float4*)&gams[base + 4];
        float g, xg;
        #define LANECH(P_, Q_, W0_, W1_, W2_, W3_, G_, EI) \
            g = P_ + Q_; g = fmaf(W0_, dist, g); g = fmaf(W1_, expd, g); \
            g = fmaf(W2_, ratio, g); g = fmaf(W3_, close, g); g = gelu_f(g); \
            s += g; s2 = fmaf(g, g, s2); xg = g * G_; afr[ks][EI] = (short)f2bf(xg);
        LANECH(Pa.x, Qa.x, w0a.x, w1a.x, w2a.x, w3a.x, ga.x, 0)
        LANECH(Pa.y, Qa.y, w0a.y, w1a.y, w2a.y, w3a.y, ga.y, 1)
        LANECH(Pa.z, Qa.z, w0a.z, w1a.z, w2a.z, w3a.z, ga.z, 2)
        LANECH(Pa.w, Qa.w, w0a.w, w1a.w, w2a.w, w3a.w, ga.w, 3)
        LANECH(Pb.x, Qb.x, w0b.x, w1b.x, w2b.x, w3b.x, gb.x, 4)
        LANECH(Pb.y, Qb.y, w0b.y, w1b.y, w2b.y, w3b.y, gb.y, 5)
        LANECH(Pb.z, Qb.z, w0b.z, w1b.z, w2b.z, w3b.z, gb.z, 6)
        LANECH(Pb.w, Qb.w, w0b.w, w1b.w, w2b.w, w3b.w, gb.w, 7)
        #undef LANECH
    }
    s  += __shfl_xor(s,  16, 64);  s  += __shfl_xor(s,  32, 64);
    s2 += __shfl_xor(s2, 16, 64);  s2 += __shfl_xor(s2, 32, 64);
    const float mu   = s * (1.f / 256.f);
    const float rstd = rsqrtf(s2 * (1.f / 256.f) - mu * mu + 1e-5f);

    f32x4 acc[8];
    #pragma unroll
    for (int ct = 0; ct < 8; ++ct) acc[ct] = (f32x4){0.f, 0.f, 0.f, 0.f};
    #pragma unroll
    for (int ks = 0; ks < 8; ++ks) {
        #pragma unroll
        for (int ct = 0; ct < 8; ++ct) {
            bf16x8 bfr = *(const bf16x8*)(W2f + (((size_t)(ct * 8 + ks)) * 64 + ln) * 8);
            acc[ct] = __builtin_amdgcn_mfma_f32_16x16x32_bf16(afr[ks], bfr, acc[ct], 0, 0, 0);
        }
    }

    float rst[4], rm[4];
    #pragma unroll
    for (int r = 0; r < 4; ++r) {
        float sr = __shfl(rstd, kg * 4 + r, 64);
        float mr = __shfl(mu,   kg * 4 + r, 64);
        rst[r] = sr; rm[r] = sr * mr;
    }
    #pragma unroll
    for (int ct = 0; ct < 8; ++ct) {
        const int col = ct * 16 + lr;
        const float ucv = us_[col], vcv = vbs[col];
        #pragma unroll
        for (int r = 0; r < 4; ++r) {
            float y = fmaf(rst[r], acc[ct][r], fmaf(-rm[r], ucv, vcv));
            y = gelu_f(y);
            const int row = wv * 16 + kg * 4 + r;
            const int chunk = col >> 3;
            const int off = row * 256 + ((chunk ^ (row & 7)) << 4) + ((col & 7) << 1);
            *(unsigned short*)((char*)Ys + off) = f2bf(y);
        }
    }

    {
        f32x4 acc3 = (f32x4){0.f, 0.f, 0.f, 0.f};
        #pragma unroll
        for (int ks = 0; ks < 4; ++ks) {
            bf16x8 bfr = *(const bf16x8*)(W3f + ((size_t)(ks * 64 + ln)) * 8);
            const int row   = wv * 16 + lr;
            const int chunk = ks * 4 + kg;
            const int off   = row * 256 + ((chunk ^ (row & 7)) << 4);
            bf16x8 afr2 = *(const bf16x8*)((char*)Ys + off);
            acc3 = __builtin_amdgcn_mfma_f32_16x16x32_bf16(afr2, bfr, acc3, 0, 0, 0);
        }
        if (lr < NBC) {
            #pragma unroll
            for (int r = 0; r < 4; ++r)
                Ls[wv * 16 + kg * 4 + r][lr] = acc3[r];
        }
    }

    const size_t adjbase  = (size_t)bi * 64 * 5;
    const size_t bondbase = ((size_t)b * 4032 + (size_t)i * 63) * 5;
    const float b30 = bb3[0], b31 = bb3[1], b32 = bb3[2], b33 = bb3[3], b34 = bb3[4];
    for (int u = ln; u < 80; u += 64) {
        const int jl = u / 5, o = u - jl * 5;
        const int j2 = wv * 16 + jl;
        float l0 = Ls[j2][0] + b30, l1 = Ls[j2][1] + b31, l2 = Ls[j2][2] + b32;
        float l3 = Ls[j2][3] + b33, l4 = Ls[j2][4] + b34;
        float mx = fmaxf(fmaxf(fmaxf(l0, l1), fmaxf(l2, l3)), l4);
        float e0 = __expf(l0 - mx), e1 = __expf(l1 - mx), e2 = __expf(l2 - mx);
        float e3 = __expf(l3 - mx), e4 = __expf(l4 - mx);
        float inv = __builtin_amdgcn_rcpf(e0 + e1 + e2 + e3 + e4);
        float lo = (o == 0) ? l0 : (o == 1) ? l1 : (o == 2) ? l2 : (o == 3) ? l3 : l4;
        float po = ((o == 0) ? e0 : (o == 1) ? e1 : (o == 2) ? e2 : (o == 3) ? e3 : e4) * inv;
        adjacency[adjbase + (size_t)j2 * 5 + o] = (j2 == i) ? ((o == 0) ? 1.f : 0.f) : po;
        if (j2 != i) {
            const int jj = j2 - (j2 > i ? 1 : 0);
            bond_logits[bondbase + (size_t)jj * 5 + o] = lo;
        }
    }
}

// ---------------------------------------------------------------------------
extern "C" void kernel_launch(void* const* d_in, const int* in_sizes, int n_in,
                              void* d_out, int out_size, void* d_ws, size_t ws_size,
                              hipStream_t stream)
{
    (void)in_sizes; (void)n_in; (void)out_size; (void)ws_size;
    const float* h   = (const float*)d_in[0];
    const float* pos = (const float*)d_in[1];
    const float* aW1 = (const float*)d_in[4];
    const float* ab1 = (const float*)d_in[5];
    const float* ag  = (const float*)d_in[6];
    const float* abn = (const float*)d_in[7];
    const float* aW2 = (const float*)d_in[8];
    const float* ab2 = (const float*)d_in[9];
    const float* aW3 = (const float*)d_in[10];
    const float* ab3 = (const float*)d_in[11];
    const float* vW1 = (const float*)d_in[12];
    const float* vb1 = (const float*)d_in[13];
    const float* vg  = (const float*)d_in[14];
    const float* vbn = (const float*)d_in[15];
    const float* vW2 = (const float*)d_in[16];
    const float* vb2 = (const float*)d_in[17];
    const float* vW3 = (const float*)d_in[18];
    const float* vb3 = (const float*)d_in[19];
    const float* bW1 = (const float*)d_in[20];
    const float* bb1 = (const float*)d_in[21];
    const float* bg  = (const float*)d_in[22];
    const float* bbn = (const float*)d_in[23];
    const float* bW2 = (const float*)d_in[24];
    const float* bb2 = (const float*)d_in[25];
    const float* bW3 = (const float*)d_in[26];
    const float* bb3 = (const float*)d_in[27];
    const float* mv  = (const float*)d_in[28];
    const float* cr  = (const float*)d_in[29];

    float* out = (float*)d_out;
    float* atom_logits = out + OFF_ATOM;
    float* bond_logits = out + OFF_BOND;
    float* valmat      = out + OFF_VALM;
    float* adjacency   = out + OFF_ADJ;

    float* ws    = (float*)d_ws;
    float* ma    = ws;                       // 4096
    float* rad   = ws + 4096;                // 4096
    float* val   = ws + 8192;                // 4096
    float* Pp    = ws + 12288;               // 1048576
    float* Qq    = ws + 1060864;             // 1048576
    float* uu    = ws + 2109440;             // 128
    float* vvb   = ws + 2109568;             // 128
    short* W2f   = (short*)(ws + 2109696);   // 32768 bf16 (16384 fl)
    short* W3f   = (short*)(ws + 2126080);   // 2048 bf16  (1024 fl)
    short* PQf   = (short*)(ws + 2127104);   // 131072 bf16 (65536 fl)
    short* V1f   = (short*)(ws + 2192640);   // 98304 bf16  (49152 fl)
    short* V2vf  = (short*)(ws + 2241792);   // 32768 bf16  (16384 fl)
    // end: 2258176 floats ≈ 9.03 MB

    k_prep<<<1161, 256, 0, stream>>>(bW1, bW2, bW3, vW1, vW2, bg, bbn, bb2,
                                     PQf, V1f, V2vf, W2f, W3f, uu, vvb);
    k_front<<<1024, 256, 0, stream>>>(h,
        aW1, ab1, ag, abn, aW2, ab2, aW3, ab3, mv, cr,
        vb1, vg, vbn, vb2, vW3, vb3, bb1,
        PQf, V1f, V2vf,
        atom_logits, ma, rad, val, Pp, Qq);
    k_back<<<4608, 256, 0, stream>>>(pos, rad, Pp, Qq, bW1, bg,
                                     W2f, W3f, bb3, uu, vvb, val, ma,
                                     bond_logits, adjacency, valmat);
}